// Round 2
// baseline (440.779 us; speedup 1.0000x reference)
//
#include <hip/hip_runtime.h>
#include <hip/hip_bf16.h>
#include <math.h>
#include <stdint.h>

// ArcFace loss via MX-fp8 (e4m3, identity scales) MFMA GEMM + fused
// fixed-max softmax. B=2048, D=512, C=50000. Output: scalar mean NLL (f32).
//
// R7: k_gemm rewritten to 256x256 tile, 8 waves, BK=128, double-buffered LDS
//     (128 KiB), ONE __syncthreads per K-step (T3-minimum schedule: stage next
//     buffer BEFORE compute of current). 128^2/2-barrier structure measured
//     18% MfmaUtil; this targets 35-50%. prep/fin unchanged (R6 forms) --
//     two different implementations of them timed identically, so they are
//     left as-is until they surface in the profile.
//
// Numerics: logits = 30*cos in [-30,30] -> fixed max 30, plain sums:
//   lse = 30 + log(sum_c exp(l_c - 30)); label logit recomputed exactly in
//   fp32 at finalize, so fp8 error only perturbs the softmax denominator.

#define B_ROWS    2048
#define D_DIM     512
#define C_CLASSES 50000
#define C_PAD     50176            // 196 * 256
#define NCHUNK    196              // 256-wide chunks
#define ARC_MARGIN 0.3f
#define ARC_SCALE  30.0f
#define ARC_EPS    1e-12f
#define K_LOG2E_S  43.2808512f     // 30 * log2(e)

// workspace layout (bytes)
#define OFF_WQ    0u               // 50176*512 = 25,690,112
#define OFF_EMBQ  25690112u        // 2048*512  =  1,048,576
#define OFF_WINV  26738688u        // 50000*4   =    200,000
#define OFF_EINV  26938688u        // 2048*4    =      8,192
#define OFF_PART  26946880u        // 2048*196*4 = 1,605,632  -> total ~28.6 MB

typedef __attribute__((ext_vector_type(8))) int   i32x8;
typedef __attribute__((ext_vector_type(4))) int   i32x4;
typedef __attribute__((ext_vector_type(4))) float f32x4;

typedef __attribute__((address_space(1))) const unsigned int g_u32;
typedef __attribute__((address_space(3))) unsigned int       l_u32;

__device__ __forceinline__ void gload_lds16(const void* g, void* l) {
    // dest is wave-uniform LDS base; HW writes lane i at base + i*16
    g_u32* gp = (g_u32*)(uintptr_t)g;
    l_u32* lp = (l_u32*)(uintptr_t)l;
    __builtin_amdgcn_global_load_lds(gp, lp, 16, 0, 0);
}

// ---------------- prep: rows -> normalized e4m3 + inverse norms ----------------
// One wave per 4 consecutive rows. Row space: [0,C_PAD) = weight (pad rows
// zero-filled), [C_PAD, C_PAD+B) = embeddings. All segments are multiples of
// 4 rows (50000, 176, 2048), so a 4-row group never straddles segments.
__global__ __launch_bounds__(256) void k_prep(const float* __restrict__ emb,
                                              const float* __restrict__ weight,
                                              uint8_t* __restrict__ embq,
                                              uint8_t* __restrict__ wq,
                                              float* __restrict__ einv,
                                              float* __restrict__ winv,
                                              float* __restrict__ out) {
    if (blockIdx.x == 0 && threadIdx.x == 0) out[0] = 0.f;  // zero for k_fin atomics
    int wave = blockIdx.x * (blockDim.x >> 6) + (threadIdx.x >> 6);
    int lane = threadIdx.x & 63;
    int g0   = wave << 2;              // first of 4 consecutive rows

    const float* src;
    uint8_t* dst;
    float* invout;
    if (g0 >= C_PAD) {                 // embedding rows
        int row = g0 - C_PAD;
        src = emb + (size_t)row * D_DIM;
        dst = embq + (size_t)row * D_DIM;
        invout = einv + row;
    } else if (g0 >= C_CLASSES) {      // zero-fill pad classes
        int2 z = make_int2(0, 0);
        #pragma unroll
        for (int r = 0; r < 4; ++r)
            *(int2*)(wq + (size_t)(g0 + r) * D_DIM + lane * 8) = z;
        return;
    } else {                           // weight rows
        src = weight + (size_t)g0 * D_DIM;
        dst = wq + (size_t)g0 * D_DIM;
        invout = winv + g0;
    }

    // issue all 8 loads before any use: 128 B/lane outstanding
    const float4* r4 = (const float4*)src;
    float4 v[8];
    #pragma unroll
    for (int r = 0; r < 4; ++r) {
        v[2 * r]     = r4[r * 128 + lane * 2];
        v[2 * r + 1] = r4[r * 128 + lane * 2 + 1];
    }

    #pragma unroll
    for (int r = 0; r < 4; ++r) {
        float4 v0 = v[2 * r], v1 = v[2 * r + 1];
        float s = v0.x*v0.x + v0.y*v0.y + v0.z*v0.z + v0.w*v0.w
                + v1.x*v1.x + v1.y*v1.y + v1.z*v1.z + v1.w*v1.w;
        #pragma unroll
        for (int off = 32; off; off >>= 1) s += __shfl_xor(s, off);
        float rn = 1.0f / fmaxf(sqrtf(s), ARC_EPS);
        if (lane == 0) invout[r] = rn;
        int p0 = __builtin_amdgcn_cvt_pk_fp8_f32(v0.x * rn, v0.y * rn, 0, false);
        p0     = __builtin_amdgcn_cvt_pk_fp8_f32(v0.z * rn, v0.w * rn, p0, true);
        int p1 = __builtin_amdgcn_cvt_pk_fp8_f32(v1.x * rn, v1.y * rn, 0, false);
        p1     = __builtin_amdgcn_cvt_pk_fp8_f32(v1.z * rn, v1.w * rn, p1, true);
        *(int2*)(dst + (size_t)r * D_DIM + lane * 8) = make_int2(p0, p1);
    }
}

struct TrueT  { static constexpr bool value = true;  };
struct FalseT { static constexpr bool value = false; };

// ---------------- GEMM (MX-fp8, identity scales) + softmax partials -----------
// 256x256 tile, 8 waves (2 N-halves x 4 M-quarters), wave tile 64x128.
// Double-buffered LDS: SMEM[buf] = [A 32KB | B 32KB]; one barrier per K-step.
// LDS cell layout per 16-row block: [kc 0..7][row 0..15] 16B cells -- lane
// order of global_load_lds matches, frag ds_read_b128 conflict-free (as R5/R6).
__global__ __launch_bounds__(512, 2) void k_gemm(const uint8_t* __restrict__ embq,
                                                 const uint8_t* __restrict__ wq,
                                                 float* __restrict__ partials) {
    __shared__ __align__(16) uint8_t SMEM[2][65536];   // 128 KiB total
    float (*Red)[2] = (float (*)[2])&SMEM[0][0];       // aliased after compute

    const int tid    = threadIdx.x;
    const int w      = tid >> 6;        // wave 0..7
    const int lane   = tid & 63;
    const int lanelo = lane & 15;
    const int quad   = lane >> 4;
    const int wr     = w >> 1;          // 0..3 : M quarter (64 rows)
    const int wc     = w & 1;           // 0..1 : N half (128 cols)

    // XCD-affinity decode: all 8 row-blocks of a chunk share id%8 -> same XCD
    // (round-robin dispatch heuristic). Per-XCD B slice ~3.2MB fits 4MB L2.
    const int id    = blockIdx.x;
    const int xcd   = id & 7;
    const int slot  = id >> 3;          // 0..199
    const int rb_   = slot & 7;         // row-block 0..7
    const int ci    = slot >> 3;        // 0..24
    const int chunk = xcd + (ci << 3);
    if (chunk >= NCHUNK) return;        // 32 pad blocks
    const int b0 = rb_ * 256;
    const int n0 = chunk * 256;

    const uint8_t* Abase = embq + (size_t)b0 * D_DIM;
    const uint8_t* Bbase = wq   + (size_t)n0 * D_DIM;

    f32x4 acc[4][8];
    #pragma unroll
    for (int i = 0; i < 4; ++i)
        #pragma unroll
        for (int j = 0; j < 8; ++j)
            acc[i][j] = (f32x4){0.f, 0.f, 0.f, 0.f};

    const int srow = lane & 15;
    const int skc  = lane >> 4;

    // stage one 256x128 A panel + 256x128 B panel (64 KB) into buffer bufsel;
    // 8 gload_lds16 per wave (4 A + 4 B), 8 waves cover rb 0..15 for each.
    auto stage = [&](int bufsel, int kt) {
        uint8_t* dstA = &SMEM[bufsel][0];
        uint8_t* dstB = &SMEM[bufsel][32768];
        const int k0 = kt * 128;
        #pragma unroll
        for (int t = 0; t < 2; ++t) {
            const int rb = w * 2 + t;                 // 0..15
            const size_t go = (size_t)(rb * 16 + srow) * D_DIM + k0;
            #pragma unroll
            for (int h = 0; h < 2; ++h) {
                const int kc = h * 4 + skc;           // 0..7
                gload_lds16(Abase + go + kc * 16, dstA + rb * 2048 + h * 1024);
                gload_lds16(Bbase + go + kc * 16, dstB + rb * 2048 + h * 1024);
            }
        }
    };

    stage(0, 0);
    __syncthreads();                    // prologue drain: buf0 resident

    #pragma unroll
    for (int kt = 0; kt < 4; ++kt) {
        const int buf = kt & 1;
        if (kt < 3) stage(buf ^ 1, kt + 1);   // issue next tile BEFORE compute

        const uint8_t* Abuf = &SMEM[buf][0];
        const uint8_t* Bbuf = &SMEM[buf][32768];

        i32x8 af[4];                    // wave's 64 A rows, this K-step
        #pragma unroll
        for (int i = 0; i < 4; ++i) {
            const int rb = wr * 4 + i;
            i32x4 lo = *(const i32x4*)&Abuf[rb * 2048 + quad * 512 + lanelo * 16];
            i32x4 hi = *(const i32x4*)&Abuf[rb * 2048 + quad * 512 + 256 + lanelo * 16];
            af[i] = (i32x8){lo[0], lo[1], lo[2], lo[3], hi[0], hi[1], hi[2], hi[3]};
        }
        #pragma unroll
        for (int j = 0; j < 8; ++j) {   // stream B frags: 32 MFMA burst
            const int rb = wc * 8 + j;
            i32x4 lo = *(const i32x4*)&Bbuf[rb * 2048 + quad * 512 + lanelo * 16];
            i32x4 hi = *(const i32x4*)&Bbuf[rb * 2048 + quad * 512 + 256 + lanelo * 16];
            i32x8 bf = (i32x8){lo[0], lo[1], lo[2], lo[3], hi[0], hi[1], hi[2], hi[3]};
            #pragma unroll
            for (int i = 0; i < 4; ++i)
                acc[i][j] = __builtin_amdgcn_mfma_scale_f32_16x16x128_f8f6f4(
                    af[i], bf, acc[i][j],
                    0, 0,          // cbsz=fp8(e4m3), blgp=fp8(e4m3)
                    0, 127,        // scale A: identity (E8M0 127 = 1.0)
                    0, 127);       // scale B: identity
        }
        __syncthreads();               // vmcnt(0)+lgkmcnt(0)+barrier: next tile
    }                                  // resident, this buffer reusable

    // epilogue: C/D layout col=lane&15, row=quad*4+reg (shape-determined).
    // Red aliases SMEM[0]: buf0's last reads completed before kt=2's barrier.
    auto epi = [&](auto maskTag) {
        constexpr bool MASK = decltype(maskTag)::value;
        #pragma unroll
        for (int i = 0; i < 4; ++i) {
            #pragma unroll
            for (int reg = 0; reg < 4; ++reg) {
                float s4 = 0.f;
                #pragma unroll
                for (int j = 0; j < 8; ++j) {
                    float t = __builtin_amdgcn_exp2f(
                        fmaf(acc[i][j][reg], K_LOG2E_S, -K_LOG2E_S));
                    if (MASK) {
                        int c = n0 + wc * 128 + j * 16 + lanelo;
                        if (c >= C_CLASSES) t = 0.f;
                    }
                    s4 += t;
                }
                #pragma unroll
                for (int off = 1; off < 16; off <<= 1)
                    s4 += __shfl_xor(s4, off);
                if (lanelo == 0)
                    Red[wr * 64 + i * 16 + quad * 4 + reg][wc] = s4;
            }
        }
    };
    if (chunk == NCHUNK - 1) epi(TrueT{}); else epi(FalseT{});
    __syncthreads();

    if (tid < 256)
        partials[(size_t)(b0 + tid) * NCHUNK + chunk] = Red[tid][0] + Red[tid][1];
}

// -------- finalize: exact label logit + partial sum -> atomic mean NLL --------
// 2 waves per row: role 0 = exact label dot, role 1 = partials sum.
__global__ __launch_bounds__(256) void k_fin(const float* __restrict__ emb,
                                             const float* __restrict__ weight,
                                             const float* __restrict__ einv,
                                             const float* __restrict__ winv,
                                             const int* __restrict__ labels,
                                             const float* __restrict__ partials,
                                             float* __restrict__ out) {
    __shared__ float s_dot[2], s_ls[2];
    int widx = threadIdx.x >> 6;       // 0..3
    int lane = threadIdx.x & 63;
    int rloc = widx & 1;               // row within block
    int role = widx >> 1;              // 0 = dot, 1 = partials
    int b    = blockIdx.x * 2 + rloc;

    if (role == 0) {
        int label = labels[b];
        const float4* e  = (const float4*)(emb + (size_t)b * D_DIM);
        const float4* wt = (const float4*)(weight + (size_t)label * D_DIM);
        float4 e0 = e[lane],  e1 = e[lane + 64];
        float4 w0 = wt[lane], w1 = wt[lane + 64];
        float dot = e0.x*w0.x + e0.y*w0.y + e0.z*w0.z + e0.w*w0.w
                  + e1.x*w1.x + e1.y*w1.y + e1.z*w1.z + e1.w*w1.w;
        #pragma unroll
        for (int off = 32; off; off >>= 1) dot += __shfl_xor(dot, off);
        if (lane == 0) s_dot[rloc] = dot;
    } else {
        float p[4];
        #pragma unroll
        for (int t = 0; t < 4; ++t) {
            int idx = lane + t * 64;
            p[t] = (idx < NCHUNK) ? partials[(size_t)b * NCHUNK + idx] : 0.f;
        }
        float ls = p[0];
        #pragma unroll
        for (int t = 1; t < 4; ++t) ls += p[t];
        #pragma unroll
        for (int off = 32; off; off >>= 1) ls += __shfl_xor(ls, off);
        if (lane == 0) s_ls[rloc] = ls;
    }
    __syncthreads();

    if (threadIdx.x < 2) {
        int r = threadIdx.x;
        int b2 = blockIdx.x * 2 + r;
        int label = labels[b2];
        float cosv   = s_dot[r] * einv[b2] * winv[label];
        float l_orig = ARC_SCALE * cosv;
        float l_adj  = ARC_SCALE * (cosv - ARC_MARGIN);
        // swap (fp8-accumulated) label term for exact margin-adjusted one
        float s_adj = s_ls[r] - __expf(l_orig - ARC_SCALE) + __expf(l_adj - ARC_SCALE);
        float v = ARC_SCALE + logf(s_adj) - l_adj;
        atomicAdd(out, v * (1.0f / (float)B_ROWS));
    }
}

extern "C" void kernel_launch(void* const* d_in, const int* in_sizes, int n_in,
                              void* d_out, int out_size, void* d_ws, size_t ws_size,
                              hipStream_t stream) {
    const float* emb    = (const float*)d_in[0];   // (2048, 512) f32
    const int*   labels = (const int*)d_in[1];     // (2048,)
    const float* weight = (const float*)d_in[2];   // (50000, 512) f32
    float* out = (float*)d_out;

    char* ws = (char*)d_ws;
    uint8_t* wq    = (uint8_t*)(ws + OFF_WQ);
    uint8_t* embq  = (uint8_t*)(ws + OFF_EMBQ);
    float* winv     = (float*)(ws + OFF_WINV);
    float* einv     = (float*)(ws + OFF_EINV);
    float* partials = (float*)(ws + OFF_PART);

    // (C_PAD + B_ROWS) rows, 4 rows/wave, 4 waves/block
    k_prep<<<(C_PAD + B_ROWS) / 16, 256, 0, stream>>>(emb, weight, embq, wq,
                                                      einv, winv, out);

    // 8 xcd slots x (8 row-blocks x 25 ci) = 1600 blocks (32 early-return)
    k_gemm<<<1600, 512, 0, stream>>>(embq, wq, partials);

    k_fin<<<B_ROWS / 2, 256, 0, stream>>>(emb, weight, einv, winv, labels,
                                          partials, out);
}